// Round 12
// baseline (228.392 us; speedup 1.0000x reference)
//
#include <hip/hip_runtime.h>
#include <stdint.h>

// TripletRankingLoss, bit-exact JAX threefry (partitionable) replication.
// R12: ONE dispatch. Every block redundantly counting-sorts targets (32 KB)
// into its own LDS (~5us prologue, no cross-block sync — R10's spin-storm
// stays banned), then runs the proven R11 rows logic from LDS. Control words
// init via atomicCAS(0xAAAAAAAA->0) — correct for poison and memset-0
// pre-states. unroll-8 BANNED (R5-R7). Budget: rows 127 + sort 5 + launch.

#define B 8192
#define K 1024
#define POISON 0xAAAAAAAAu

struct TFOut { uint32_t a, b; };

__host__ __device__ constexpr uint32_t rotl32(uint32_t x, int r) {
    return (x << r) | (x >> (32 - r));
}

// Full Threefry-2x32 (20 rounds), exactly as jax/_src/prng.py — compile-time
// only, to derive the split keys.
__host__ __device__ constexpr TFOut threefry_full(uint32_t k0, uint32_t k1,
                                                  uint32_t x0, uint32_t x1) {
    const uint32_t ks2 = k0 ^ k1 ^ 0x1BD11BDAu;
    x0 += k0; x1 += k1;
    x0 += x1; x1 = rotl32(x1,13); x1 ^= x0;
    x0 += x1; x1 = rotl32(x1,15); x1 ^= x0;
    x0 += x1; x1 = rotl32(x1,26); x1 ^= x0;
    x0 += x1; x1 = rotl32(x1,6);  x1 ^= x0;
    x0 += k1; x1 += ks2 + 1u;
    x0 += x1; x1 = rotl32(x1,17); x1 ^= x0;
    x0 += x1; x1 = rotl32(x1,29); x1 ^= x0;
    x0 += x1; x1 = rotl32(x1,16); x1 ^= x0;
    x0 += x1; x1 = rotl32(x1,24); x1 ^= x0;
    x0 += ks2; x1 += k0 + 2u;
    x0 += x1; x1 = rotl32(x1,13); x1 ^= x0;
    x0 += x1; x1 = rotl32(x1,15); x1 ^= x0;
    x0 += x1; x1 = rotl32(x1,26); x1 ^= x0;
    x0 += x1; x1 = rotl32(x1,6);  x1 ^= x0;
    x0 += k0; x1 += k1 + 3u;
    x0 += x1; x1 = rotl32(x1,17); x1 ^= x0;
    x0 += x1; x1 = rotl32(x1,29); x1 ^= x0;
    x0 += x1; x1 = rotl32(x1,16); x1 ^= x0;
    x0 += x1; x1 = rotl32(x1,24); x1 ^= x0;
    x0 += k1; x1 += ks2 + 4u;
    x0 += x1; x1 = rotl32(x1,13); x1 ^= x0;
    x0 += x1; x1 = rotl32(x1,15); x1 ^= x0;
    x0 += x1; x1 = rotl32(x1,26); x1 ^= x0;
    x0 += x1; x1 = rotl32(x1,6);  x1 ^= x0;
    x0 += ks2; x1 += k0 + 5u;
    return TFOut{x0, x1};
}

// jax.random.key(42) -> (0,42); partitionable split: kp=block(0,0), kn=block(0,1).
constexpr TFOut KP = threefry_full(0u, 42u, 0u, 0u);
constexpr TFOut KN = threefry_full(0u, 42u, 0u, 1u);

// Device-fast threefry: x0=0 implicit, keys compile-time, caller passes
// x1 pre-keyed (= f + K1). alignbit guarantees 1-inst rotates.
template<uint32_t TK0, uint32_t TK1>
__device__ __forceinline__ uint32_t tf_bits(uint32_t x1) {
    constexpr uint32_t KS2 = TK0 ^ TK1 ^ 0x1BD11BDAu;
    uint32_t x0 = TK0;
#define RND(r) x0 += x1; x1 = __builtin_amdgcn_alignbit(x1, x1, 32 - (r)); x1 ^= x0;
    RND(13) RND(15) RND(26) RND(6)
    x0 += TK1; x1 += KS2 + 1u;
    RND(17) RND(29) RND(16) RND(24)
    x0 += KS2; x1 += TK0 + 2u;
    RND(13) RND(15) RND(26) RND(6)
    x0 += TK0; x1 += TK1 + 3u;
    RND(17) RND(29) RND(16) RND(24)
    x0 += TK1; x1 += KS2 + 4u;
    RND(13) RND(15) RND(26) RND(6)
    x0 += KS2; x1 += TK0 + 5u;
#undef RND
    return x0 ^ x1;
}

__device__ __forceinline__ void mrg(uint32_t& H, uint32_t& J, uint32_t h2, uint32_t j2) {
    if (h2 > H || (h2 == H && j2 < J)) { H = h2; J = j2; }  // j tie: smaller wins
}

// Unchecked-zone scan over LDS-resident sorted indices. Unroll-4, preload
// next group; over-read reaches at most entry end+255 <= 8447 — si is padded
// to 8448 entries (loads discarded, stay in-bounds of the LDS array).
template<uint32_t TK0, uint32_t TK1>
__device__ __forceinline__ void scan_main(const uint16_t* idx,
                                          int beg, int end, int lane,
                                          uint32_t kb, uint32_t& H, uint32_t& J)
{
    uint32_t h0 = 0, h1 = 0, h2 = 0, h3 = 0;
    uint32_t j0 = 0xFFFFFFFFu, j1 = 0xFFFFFFFFu, j2 = 0xFFFFFFFFu, j3 = 0xFFFFFFFFu;
    int s = beg;
    uint32_t a = 0, b = 0, c = 0, d = 0;
    if (s + 256 <= end) {
        a = idx[s + lane];       b = idx[s + lane + 64];
        c = idx[s + lane + 128]; d = idx[s + lane + 192];
    }
    while (s + 256 <= end) {
        const int sn = s + 256;
        const uint32_t na = idx[sn + lane];        // in flight across the 4 hashes
        const uint32_t nb = idx[sn + lane + 64];
        const uint32_t nc = idx[sn + lane + 128];
        const uint32_t nd = idx[sn + lane + 192];
        const uint32_t ha = tf_bits<TK0, TK1>(a + kb) >> 9;
        const uint32_t hb = tf_bits<TK0, TK1>(b + kb) >> 9;
        const uint32_t hc = tf_bits<TK0, TK1>(c + kb) >> 9;
        const uint32_t hd = tf_bits<TK0, TK1>(d + kb) >> 9;
        if (ha > h0) { h0 = ha; j0 = a; }
        if (hb > h1) { h1 = hb; j1 = b; }
        if (hc > h2) { h2 = hc; j2 = c; }
        if (hd > h3) { h3 = hd; j3 = d; }
        a = na; b = nb; c = nc; d = nd;
        s = sn;
    }
    for (int t = s + lane; t < end; t += 64) {
        const uint32_t j = idx[t];
        const uint32_t hh = tf_bits<TK0, TK1>(j + kb) >> 9;
        if (hh > h0) { h0 = hh; j0 = j; }
    }
    mrg(h0, j0, h1, j1); mrg(h2, j2, h3, j3); mrg(h0, j0, h2, j2);
    mrg(H, J, h0, j0);
}

// Boundary zone (~16 elems/row): exact fp32 predicate; tj gathered from
// L1-resident targets[] (32 KB).
template<uint32_t TK0, uint32_t TK1, bool NEG>
__device__ __forceinline__ void scan_bnd(const float* __restrict__ targets,
                                         const uint16_t* idx,
                                         int beg, int end, int lane, float ti,
                                         uint32_t kb, uint32_t& H, uint32_t& J,
                                         bool& found)
{
    for (int t = beg + lane; t < end; t += 64) {
        const uint32_t j = idx[t];
        const float tj = targets[j];
        const uint32_t hh = tf_bits<TK0, TK1>(j + kb) >> 9;
        const float dd = ti - tj;
        const bool ok = NEG ? (dd > 0.1f) : (dd < -0.1f);
        if (ok) {
            found = true;
            if (hh > H || (hh == H && j < J)) { H = hh; J = j; }
        }
    }
}

__device__ __forceinline__ int bin_of(float v) {
    int b = (int)(v * (float)K);
    return b < 0 ? 0 : (b > K - 1 ? K - 1 : b);
}

// ---------------- Single fused kernel (no cross-block sync) ------------------
__global__ __launch_bounds__(256) void fused_kernel(
    const float* __restrict__ preds, const float* __restrict__ targets,
    float* __restrict__ loss_sum, float* __restrict__ valid_sum,
    unsigned int* __restrict__ done, float* __restrict__ out)
{
    __shared__ __align__(16) uint16_t si[8448];  // sorted idx + over-read pad
    __shared__ int bs[K + 1];                    // bin_start
    __shared__ int cur[K];                       // hist, then cursor
    __shared__ int wsum4[4];
    __shared__ float sl[4], sv[4];

    const int tid = threadIdx.x;

    // ===== block-local counting sort of targets into LDS =====
    for (int i = tid; i < K; i += 256) cur[i] = 0;
    __syncthreads();
    const float4* t4 = reinterpret_cast<const float4*>(targets);
    for (int i = 0; i < 8; ++i) {                 // 32 elems/thread histogram
        const float4 va = t4[tid + i * 256];
        atomicAdd(&cur[bin_of(va.x)], 1);
        atomicAdd(&cur[bin_of(va.y)], 1);
        atomicAdd(&cur[bin_of(va.z)], 1);
        atomicAdd(&cur[bin_of(va.w)], 1);
    }
    __syncthreads();

    // Scan: thread t owns bins 4t..4t+3 (proven R9 scan structure).
    const int lane = tid & 63;
    const int wv   = tid >> 6;
    {
        const int c0 = cur[4 * tid], c1 = cur[4 * tid + 1];
        const int c2 = cur[4 * tid + 2], c3 = cur[4 * tid + 3];
        const int s4 = c0 + c1 + c2 + c3;
        int incl = s4;
        for (int d = 1; d < 64; d <<= 1) {
            const int o = __shfl_up(incl, d, 64);
            if (lane >= d) incl += o;
        }
        if (lane == 63) wsum4[wv] = incl;
        __syncthreads();
        int wbase = 0;
        for (int w = 0; w < wv; ++w) wbase += wsum4[w];
        incl += wbase;
        const int excl = incl - s4;
        if (tid == 0) bs[0] = 0;
        bs[4 * tid + 1] = excl + c0;
        bs[4 * tid + 2] = excl + c0 + c1;
        bs[4 * tid + 3] = excl + c0 + c1 + c2;
        bs[4 * tid + 4] = excl + s4;
        cur[4 * tid + 0] = excl;
        cur[4 * tid + 1] = excl + c0;
        cur[4 * tid + 2] = excl + c0 + c1;
        cur[4 * tid + 3] = excl + c0 + c1 + c2;
    }
    __syncthreads();

    // Scatter indices into LDS (values re-loaded from L1-hot targets).
    for (int i = 0; i < 8; ++i) {
        const int g = tid + i * 256;
        const float4 va = t4[g];
        const int e = 4 * g;
        int p;
        p = atomicAdd(&cur[bin_of(va.x)], 1); si[p] = (uint16_t)(e);
        p = atomicAdd(&cur[bin_of(va.y)], 1); si[p] = (uint16_t)(e + 1);
        p = atomicAdd(&cur[bin_of(va.z)], 1); si[p] = (uint16_t)(e + 2);
        p = atomicAdd(&cur[bin_of(va.w)], 1); si[p] = (uint16_t)(e + 3);
    }
    __syncthreads();

    // ===== rows phase (logic identical to R11, sources from LDS) =====
    const int row = ((int)blockIdx.x << 2) + wv;
    const float ti = targets[row];
    const uint32_t base = (uint32_t)row << 13;   // row * B

    const float cutn = ti - 0.1f;
    int bl = (int)floorf((cutn - 1e-4f) * (float)K);
    int bh = (int)floorf((cutn + 1e-4f) * (float)K) + 1;
    bl = bl < 0 ? 0 : (bl > K ? K : bl);
    bh = bh < 0 ? 0 : (bh > K ? K : bh);
    const int un_end = bs[bl];   // unchecked neg: [0, un_end)
    const int cn_end = bs[bh];   // checked  neg: [un_end, cn_end)

    const float cutp = ti + 0.1f;
    int pl = (int)floorf((cutp - 1e-4f) * (float)K);
    int ph = (int)floorf((cutp + 1e-4f) * (float)K) + 1;
    pl = pl < 0 ? 0 : (pl > K ? K : pl);
    ph = ph < 0 ? 0 : (ph > K ? K : ph);
    const int cp_beg = bs[pl];   // checked  pos: [cp_beg, up_beg)
    const int up_beg = bs[ph];   // unchecked pos: [up_beg, B)

    uint32_t Hn = 0, Jn = 0xFFFFFFFFu;
    bool fn = false;
    scan_main<KN.a, KN.b>(si, 0, un_end, lane, base + KN.b, Hn, Jn);
    scan_bnd<KN.a, KN.b, true>(targets, si, un_end, cn_end, lane, ti,
                               base + KN.b, Hn, Jn, fn);
    const bool valid_n = (un_end > 0) || __any(fn);

    uint32_t Hp = 0, Jp = 0xFFFFFFFFu;
    bool fp2 = false;
    scan_main<KP.a, KP.b>(si, up_beg, B, lane, base + KP.b, Hp, Jp);
    scan_bnd<KP.a, KP.b, false>(targets, si, cp_beg, up_beg, lane, ti,
                                base + KP.b, Hp, Jp, fp2);
    const bool valid_p = (up_beg < B) || __any(fp2);

    for (int off = 32; off > 0; off >>= 1) {
        const uint32_t ohn = __shfl_down(Hn, off, 64);
        const uint32_t ojn = __shfl_down(Jn, off, 64);
        if (ohn > Hn || (ohn == Hn && ojn < Jn)) { Hn = ohn; Jn = ojn; }
        const uint32_t ohp = __shfl_down(Hp, off, 64);
        const uint32_t ojp = __shfl_down(Jp, off, 64);
        if (ohp > Hp || (ohp == Hp && ojp < Jp)) { Hp = ohp; Jp = ojp; }
    }

    if (lane == 0) {
        float loss = 0.0f, valid = 0.0f;
        if (valid_n && valid_p) {
            const float per = 0.5f - (preds[Jp & 8191u] - preds[Jn & 8191u]);
            loss = per > 0.0f ? per : 0.0f;
            valid = 1.0f;
        }
        sl[wv] = loss; sv[wv] = valid;
    }
    __syncthreads();
    if (tid == 0) {
        // One-time poison->0 transform (exactly one block wins each word;
        // also correct if the harness pre-zeroed ws). Every block CASes
        // before adding, so no add ever lands on poison.
        atomicCAS((unsigned int*)loss_sum,  POISON, 0u);
        atomicCAS((unsigned int*)valid_sum, POISON, 0u);
        atomicCAS(done, POISON, 0u);
        atomicAdd(loss_sum,  sl[0] + sl[1] + sl[2] + sl[3]);
        atomicAdd(valid_sum, sv[0] + sv[1] + sv[2] + sv[3]);
        __threadfence();
        const unsigned int old = atomicAdd(done, 1u);
        if (old == gridDim.x - 1u) {          // last block finalizes
            const float ls = atomicAdd(loss_sum, 0.0f);
            const float vs = atomicAdd(valid_sum, 0.0f);
            out[0] = vs > 0.0f ? ls / fmaxf(vs, 1.0f) : 0.0f;
        }
    }
}

extern "C" void kernel_launch(void* const* d_in, const int* in_sizes, int n_in,
                              void* d_out, int out_size, void* d_ws, size_t ws_size,
                              hipStream_t stream) {
    const float* preds   = (const float*)d_in[0];
    const float* targets = (const float*)d_in[1];

    float* ws = (float*)d_ws;
    float*        loss_sum  = ws;
    float*        valid_sum = ws + 1;
    unsigned int* done      = (unsigned int*)(ws + 2);

    fused_kernel<<<B / 4, 256, 0, stream>>>(preds, targets, loss_sum, valid_sum,
                                            done, (float*)d_out);
}

// Round 13
// 174.181 us; speedup vs baseline: 1.3112x; 1.3112x over previous
//
#include <hip/hip_runtime.h>
#include <stdint.h>

// TripletRankingLoss, bit-exact JAX threefry (partitionable) replication.
// R13 = R11 champion (173.7us) + slimmer sort: indices-only counting sort
// (no sorted_t array at all — boundary zone gathers targets[j] from L1;
// value identical by construction). 2 dispatches (proven floor structure:
// R10 spin-sync 3.4x regression, R12 redundant-sort +55us regression).
// unroll-8 BANNED (R5-R7 compile-level poison).
// Time model: rows 127.5 (hash-issue floor, ~2.35us/M-hash, 5 structures
// invariant) + sort ~15 + fixed ~20.

#define B 8192
#define K 1024

struct TFOut { uint32_t a, b; };

__host__ __device__ constexpr uint32_t rotl32(uint32_t x, int r) {
    return (x << r) | (x >> (32 - r));
}

// Full Threefry-2x32 (20 rounds), exactly as jax/_src/prng.py — compile-time
// only, to derive the split keys.
__host__ __device__ constexpr TFOut threefry_full(uint32_t k0, uint32_t k1,
                                                  uint32_t x0, uint32_t x1) {
    const uint32_t ks2 = k0 ^ k1 ^ 0x1BD11BDAu;
    x0 += k0; x1 += k1;
    x0 += x1; x1 = rotl32(x1,13); x1 ^= x0;
    x0 += x1; x1 = rotl32(x1,15); x1 ^= x0;
    x0 += x1; x1 = rotl32(x1,26); x1 ^= x0;
    x0 += x1; x1 = rotl32(x1,6);  x1 ^= x0;
    x0 += k1; x1 += ks2 + 1u;
    x0 += x1; x1 = rotl32(x1,17); x1 ^= x0;
    x0 += x1; x1 = rotl32(x1,29); x1 ^= x0;
    x0 += x1; x1 = rotl32(x1,16); x1 ^= x0;
    x0 += x1; x1 = rotl32(x1,24); x1 ^= x0;
    x0 += ks2; x1 += k0 + 2u;
    x0 += x1; x1 = rotl32(x1,13); x1 ^= x0;
    x0 += x1; x1 = rotl32(x1,15); x1 ^= x0;
    x0 += x1; x1 = rotl32(x1,26); x1 ^= x0;
    x0 += x1; x1 = rotl32(x1,6);  x1 ^= x0;
    x0 += k0; x1 += k1 + 3u;
    x0 += x1; x1 = rotl32(x1,17); x1 ^= x0;
    x0 += x1; x1 = rotl32(x1,29); x1 ^= x0;
    x0 += x1; x1 = rotl32(x1,16); x1 ^= x0;
    x0 += x1; x1 = rotl32(x1,24); x1 ^= x0;
    x0 += k1; x1 += ks2 + 4u;
    x0 += x1; x1 = rotl32(x1,13); x1 ^= x0;
    x0 += x1; x1 = rotl32(x1,15); x1 ^= x0;
    x0 += x1; x1 = rotl32(x1,26); x1 ^= x0;
    x0 += x1; x1 = rotl32(x1,6);  x1 ^= x0;
    x0 += ks2; x1 += k0 + 5u;
    return TFOut{x0, x1};
}

// jax.random.key(42) -> (0,42); partitionable split: kp=block(0,0), kn=block(0,1).
constexpr TFOut KP = threefry_full(0u, 42u, 0u, 0u);
constexpr TFOut KN = threefry_full(0u, 42u, 0u, 1u);

// Device-fast threefry: x0=0 implicit, keys compile-time, caller passes
// x1 pre-keyed (= f + K1). alignbit guarantees 1-inst rotates.
template<uint32_t TK0, uint32_t TK1>
__device__ __forceinline__ uint32_t tf_bits(uint32_t x1) {
    constexpr uint32_t KS2 = TK0 ^ TK1 ^ 0x1BD11BDAu;
    uint32_t x0 = TK0;
#define RND(r) x0 += x1; x1 = __builtin_amdgcn_alignbit(x1, x1, 32 - (r)); x1 ^= x0;
    RND(13) RND(15) RND(26) RND(6)
    x0 += TK1; x1 += KS2 + 1u;
    RND(17) RND(29) RND(16) RND(24)
    x0 += KS2; x1 += TK0 + 2u;
    RND(13) RND(15) RND(26) RND(6)
    x0 += TK0; x1 += TK1 + 3u;
    RND(17) RND(29) RND(16) RND(24)
    x0 += TK1; x1 += KS2 + 4u;
    RND(13) RND(15) RND(26) RND(6)
    x0 += KS2; x1 += TK0 + 5u;
#undef RND
    return x0 ^ x1;
}

__device__ __forceinline__ void mrg(uint32_t& H, uint32_t& J, uint32_t h2, uint32_t j2) {
    if (h2 > H || (h2 == H && j2 < J)) { H = h2; J = j2; }  // j tie: smaller wins
}

// Unchecked-zone scan: every element passes the predicate by construction.
// Unroll-4, preload next group (over-read past `end` stays inside d_ws slack).
template<uint32_t TK0, uint32_t TK1>
__device__ __forceinline__ void scan_main(const uint16_t* __restrict__ idx,
                                          int beg, int end, int lane,
                                          uint32_t kb, uint32_t& H, uint32_t& J)
{
    uint32_t h0 = 0, h1 = 0, h2 = 0, h3 = 0;
    uint32_t j0 = 0xFFFFFFFFu, j1 = 0xFFFFFFFFu, j2 = 0xFFFFFFFFu, j3 = 0xFFFFFFFFu;
    int s = beg;
    uint32_t a = 0, b = 0, c = 0, d = 0;
    if (s + 256 <= end) {
        a = idx[s + lane];       b = idx[s + lane + 64];
        c = idx[s + lane + 128]; d = idx[s + lane + 192];
    }
    while (s + 256 <= end) {
        const int sn = s + 256;
        const uint32_t na = idx[sn + lane];        // in flight across the 4 hashes
        const uint32_t nb = idx[sn + lane + 64];
        const uint32_t nc = idx[sn + lane + 128];
        const uint32_t nd = idx[sn + lane + 192];
        const uint32_t ha = tf_bits<TK0, TK1>(a + kb) >> 9;
        const uint32_t hb = tf_bits<TK0, TK1>(b + kb) >> 9;
        const uint32_t hc = tf_bits<TK0, TK1>(c + kb) >> 9;
        const uint32_t hd = tf_bits<TK0, TK1>(d + kb) >> 9;
        if (ha > h0) { h0 = ha; j0 = a; }
        if (hb > h1) { h1 = hb; j1 = b; }
        if (hc > h2) { h2 = hc; j2 = c; }
        if (hd > h3) { h3 = hd; j3 = d; }
        a = na; b = nb; c = nc; d = nd;
        s = sn;
    }
    for (int t = s + lane; t < end; t += 64) {
        const uint32_t j = idx[t];
        const uint32_t hh = tf_bits<TK0, TK1>(j + kb) >> 9;
        if (hh > h0) { h0 = hh; j0 = j; }
    }
    mrg(h0, j0, h1, j1); mrg(h2, j2, h3, j3); mrg(h0, j0, h2, j2);
    mrg(H, J, h0, j0);
}

// Boundary zone (~16 elems/row): exact fp32 predicate; tj gathered from
// targets[] (L1-resident 32 KB) — identical value to the old sorted_t[t].
template<uint32_t TK0, uint32_t TK1, bool NEG>
__device__ __forceinline__ void scan_bnd(const float* __restrict__ targets,
                                         const uint16_t* __restrict__ idx,
                                         int beg, int end, int lane, float ti,
                                         uint32_t kb, uint32_t& H, uint32_t& J,
                                         bool& found)
{
    for (int t = beg + lane; t < end; t += 64) {
        const uint32_t j = idx[t];
        const float tj = targets[j];
        const uint32_t hh = tf_bits<TK0, TK1>(j + kb) >> 9;
        const float dd = ti - tj;
        const bool ok = NEG ? (dd > 0.1f) : (dd < -0.1f);
        if (ok) {
            found = true;
            if (hh > H || (hh == H && j < J)) { H = hh; J = j; }
        }
    }
}

// ------------- Kernel A: indices-only LDS-staged counting sort --------------
// Single block, 1024 threads. Scatter u16 indices into LDS, dump coalesced.
__global__ __launch_bounds__(1024) void sort_kernel(
    const float* __restrict__ targets,
    uint16_t* __restrict__ sorted_idx, int* __restrict__ bin_start,
    float* __restrict__ loss_sum, float* __restrict__ valid_sum,
    unsigned int* __restrict__ done)
{
    __shared__ int hist[K];                       //  4 KB
    __shared__ int cursor[K];                     //  4 KB
    __shared__ int wsum[16];
    __shared__ __align__(16) uint16_t si_lds[B];  // 16 KB  (total ~24 KB)
    const int tid = threadIdx.x;

    hist[tid] = 0;
    if (tid == 0) { *loss_sum = 0.0f; *valid_sum = 0.0f; *done = 0u; }
    __syncthreads();

    // Load 8 elements/thread as 2x float4 (coalesced).
    const float4* t4 = reinterpret_cast<const float4*>(targets);
    const float4 va = t4[tid];
    const float4 vb = t4[tid + 1024];
    float v[8] = {va.x, va.y, va.z, va.w, vb.x, vb.y, vb.z, vb.w};
    int   bn[8];
#pragma unroll
    for (int i = 0; i < 8; ++i) {
        int b = (int)(v[i] * (float)K);
        b = b < 0 ? 0 : (b > K - 1 ? K - 1 : b);
        bn[i] = b;
        atomicAdd(&hist[b], 1);
    }
    __syncthreads();

    // shfl-based inclusive scan over 1024 bins (1 bin/thread) — proven code.
    const int cnt  = hist[tid];
    const int lane = tid & 63;
    const int wv   = tid >> 6;
    int incl = cnt;
    for (int d = 1; d < 64; d <<= 1) {
        const int o = __shfl_up(incl, d, 64);
        if (lane >= d) incl += o;
    }
    if (lane == 63) wsum[wv] = incl;
    __syncthreads();
    if (tid < 16) {
        int wincl = wsum[tid];
        for (int d = 1; d < 16; d <<= 1) {
            const int o = __shfl_up(wincl, d, 64);
            if (tid >= d) wincl += o;
        }
        wsum[tid] = wincl;
    }
    __syncthreads();
    incl += (wv > 0) ? wsum[wv - 1] : 0;
    bin_start[tid + 1] = incl;
    if (tid == 0) bin_start[0] = 0;
    cursor[tid] = incl - cnt;
    __syncthreads();

    // Scatter indices into LDS staging.
    // Element id for v[i]: i<4 -> 4*tid+i ; i>=4 -> 4096 + 4*tid + (i-4).
#pragma unroll
    for (int i = 0; i < 8; ++i) {
        const int e = (i < 4) ? (4 * tid + i) : (4096 + 4 * tid + (i - 4));
        const int p = atomicAdd(&cursor[bn[i]], 1);
        si_lds[p] = (uint16_t)e;
    }
    __syncthreads();

    // Coalesced dump to global (8192 u16 = 1024 uint4).
    reinterpret_cast<uint4*>(sorted_idx)[tid] = reinterpret_cast<uint4*>(si_lds)[tid];
}

// ------------- Kernel B: per-wave row scan + fused finalize -----------------
// (logic identical to R11; boundary gathers targets[j] instead of sorted_t[t])
__global__ __launch_bounds__(256) void rows_kernel(
    const float* __restrict__ preds, const float* __restrict__ targets,
    const uint16_t* __restrict__ sorted_idx, const int* __restrict__ bin_start,
    float* __restrict__ loss_sum, float* __restrict__ valid_sum,
    unsigned int* __restrict__ done, float* __restrict__ out)
{
    __shared__ float sl[4], sv[4];
    const int lane = threadIdx.x & 63;
    const int wv   = threadIdx.x >> 6;
    const int row  = (blockIdx.x << 2) + wv;

    const float ti = targets[row];
    const uint32_t base = (uint32_t)row << 13;   // row * B

    // Candidate ranges from bins (1e-4 conservative margin >> fp32 ulp slack;
    // boundary zone gets the exact fp32 predicate).
    const float cutn = ti - 0.1f;
    int bl = (int)floorf((cutn - 1e-4f) * (float)K);
    int bh = (int)floorf((cutn + 1e-4f) * (float)K) + 1;
    bl = bl < 0 ? 0 : (bl > K ? K : bl);
    bh = bh < 0 ? 0 : (bh > K ? K : bh);
    const int un_end = bin_start[bl];   // unchecked neg: [0, un_end)
    const int cn_end = bin_start[bh];   // checked  neg: [un_end, cn_end)

    const float cutp = ti + 0.1f;
    int pl = (int)floorf((cutp - 1e-4f) * (float)K);
    int ph = (int)floorf((cutp + 1e-4f) * (float)K) + 1;
    pl = pl < 0 ? 0 : (pl > K ? K : pl);
    ph = ph < 0 ? 0 : (ph > K ? K : ph);
    const int cp_beg = bin_start[pl];   // checked  pos: [cp_beg, up_beg)
    const int up_beg = bin_start[ph];   // unchecked pos: [up_beg, B)

    uint32_t Hn = 0, Jn = 0xFFFFFFFFu;
    bool fn = false;
    scan_main<KN.a, KN.b>(sorted_idx, 0, un_end, lane, base + KN.b, Hn, Jn);
    scan_bnd<KN.a, KN.b, true>(targets, sorted_idx, un_end, cn_end, lane, ti,
                               base + KN.b, Hn, Jn, fn);
    const bool valid_n = (un_end > 0) || __any(fn);

    uint32_t Hp = 0, Jp = 0xFFFFFFFFu;
    bool fp2 = false;
    scan_main<KP.a, KP.b>(sorted_idx, up_beg, B, lane, base + KP.b, Hp, Jp);
    scan_bnd<KP.a, KP.b, false>(targets, sorted_idx, cp_beg, up_beg, lane, ti,
                                base + KP.b, Hp, Jp, fp2);
    const bool valid_p = (up_beg < B) || __any(fp2);

    // In-wave (h, j) max-reduction with first-index tie-break.
    for (int off = 32; off > 0; off >>= 1) {
        const uint32_t ohn = __shfl_down(Hn, off, 64);
        const uint32_t ojn = __shfl_down(Jn, off, 64);
        if (ohn > Hn || (ohn == Hn && ojn < Jn)) { Hn = ohn; Jn = ojn; }
        const uint32_t ohp = __shfl_down(Hp, off, 64);
        const uint32_t ojp = __shfl_down(Jp, off, 64);
        if (ohp > Hp || (ohp == Hp && ojp < Jp)) { Hp = ohp; Jp = ojp; }
    }

    if (lane == 0) {
        float loss = 0.0f, valid = 0.0f;
        if (valid_n && valid_p) {
            const float per = 0.5f - (preds[Jp & 8191u] - preds[Jn & 8191u]);
            loss = per > 0.0f ? per : 0.0f;
            valid = 1.0f;
        }
        sl[wv] = loss; sv[wv] = valid;
    }
    __syncthreads();
    if (threadIdx.x == 0) {
        atomicAdd(loss_sum,  sl[0] + sl[1] + sl[2] + sl[3]);
        atomicAdd(valid_sum, sv[0] + sv[1] + sv[2] + sv[3]);
        __threadfence();
        const unsigned int old = atomicAdd(done, 1u);
        if (old == gridDim.x - 1u) {          // last block finalizes
            const float ls = atomicAdd(loss_sum, 0.0f);
            const float vs = atomicAdd(valid_sum, 0.0f);
            out[0] = vs > 0.0f ? ls / fmaxf(vs, 1.0f) : 0.0f;
        }
    }
}

extern "C" void kernel_launch(void* const* d_in, const int* in_sizes, int n_in,
                              void* d_out, int out_size, void* d_ws, size_t ws_size,
                              hipStream_t stream) {
    const float* preds   = (const float*)d_in[0];
    const float* targets = (const float*)d_in[1];

    // Workspace (float-word offsets); watermark ~25.4 KB.
    float* ws = (float*)d_ws;
    uint16_t*     sorted_idx = (uint16_t*)ws;            // words 0..4095 (16 KB)
    //            unroll-4 over-read slack: words 4096..4223 (256 u16 entries)
    int*          bin_start  = (int*)(ws + 4224);        // 1025 ints -> 5249
    float*        loss_sum   = ws + 5280;
    float*        valid_sum  = ws + 5281;
    unsigned int* done       = (unsigned int*)(ws + 5282);

    sort_kernel<<<1, 1024, 0, stream>>>(targets, sorted_idx, bin_start,
                                        loss_sum, valid_sum, done);
    rows_kernel<<<B / 4, 256, 0, stream>>>(preds, targets, sorted_idx, bin_start,
                                           loss_sum, valid_sum, done,
                                           (float*)d_out);
}